// Round 7
// baseline (115.952 us; speedup 1.0000x reference)
//
#include <hip/hip_runtime.h>
#include <math.h>

// Problem constants (reference: S=256, B=2, HID=512, NH=8, HD=64, C=1)
constexpr int S_   = 256;
constexpr int B_   = 2;
constexpr int HID_ = 512;
constexpr int NH_  = 8;
constexpr int HD_  = 64;
constexpr int BSH  = B_ * S_ * HID_;   // 262144

// Measured attribution: gemm=5.2us (R5 probe), attn v1=39us (R5), v2~37us (R6
// delta). attn v1/v2 identical speed despite occupancy/chain restructure =>
// the cost is per-n LDS re-reads + mid-chain shfl + (v2) spill risk. v3 kills
// all three: kv in regs, q via scalar loads, no LDS/shfl in the hot loop.

typedef unsigned short u16;
typedef short s16x8 __attribute__((ext_vector_type(8)));
typedef float f32x4 __attribute__((ext_vector_type(4)));

__device__ __forceinline__ float artanh_c(float x) {
    // reference _artanh: clip to [-1+1e-7, 1-1e-7], then artanh
    x = fminf(fmaxf(x, -0.9999999f), 0.9999999f);
    return 0.5f * __logf((1.f + x) / (1.f - x));
}

__device__ __forceinline__ float wsum64(float v) {
    #pragma unroll
    for (int o = 1; o < 64; o <<= 1) v += __shfl_xor(v, o, 64);
    return v;
}

__device__ __forceinline__ float block_sum_256(float v, float* red) {
    const int t = threadIdx.x;
    __syncthreads();              // protect previous use of red
    red[t] = v;
    __syncthreads();
    #pragma unroll
    for (int sft = 128; sft > 0; sft >>= 1) {
        if (t < sft) red[t] += red[t + sft];
        __syncthreads();
    }
    return red[0];
}

// fp32 -> bf16 hi/lo split (exact residual: a = hi + lo + O(2^-16 a))
__device__ __forceinline__ void split8(const float* v, s16x8& hi, s16x8& lo) {
    #pragma unroll
    for (int j = 0; j < 8; ++j) {
        const unsigned u = __float_as_uint(v[j]);
        const float hf = __uint_as_float(u & 0xFFFF0000u);
        hi[j] = (short)(u >> 16);
        lo[j] = (short)(__float_as_uint(v[j] - hf) >> 16);
    }
}

// ---------------------------------------------------------------------------
// Stage 1a: mx = x @ W^T via bf16 MFMA, hi/lo compensated (R4 structure,
// measured 5.2us in the R5 probe).
// ---------------------------------------------------------------------------
__global__ __launch_bounds__(256) void gemm3_fused_kernel(
    const float* __restrict__ query,
    const float* __restrict__ Wq, const float* __restrict__ Wk,
    const float* __restrict__ Wv, float* __restrict__ ws_mx)
{
    const int tid = threadIdx.x;
    const int rt = blockIdx.x >> 3;            // 0..47 (32-row tiles over 1536)
    const int ct = blockIdx.x & 7;             // 0..7  (64-col tiles)
    const int which = (rt * 32) >> 9;
    const int rloc  = (rt * 32) & 511;
    const float* __restrict__ W = (which == 0) ? Wq : (which == 1) ? Wk : Wv;

    __shared__ __align__(16) u16 sA[2][2][32 * 64];   // [buf][hi/lo] 16 KB
    __shared__ __align__(16) u16 sB[2][2][64 * 64];   // [buf][hi/lo] 32 KB

    // staging: A thread -> (row ra, slice sa); B thread -> (row rb, slices hb,hb+1)
    const int ra = tid >> 3, sa = tid & 7;
    const int rb = tid >> 2, hb = (tid & 3) * 2;
    const int axrow = rloc + ra;
    const float* gA = query + (size_t)((axrow & 255) * 2 + (axrow >> 8)) * HID_ + sa * 8;
    const float* gB = W + (size_t)(ct * 64 + rb) * HID_ + hb * 8;
    const int wA  = ra * 64 + ((sa ^ (ra & 7)) * 8);
    const int wB0 = rb * 64 + ((hb ^ (rb & 7)) * 8);
    const int wB1 = rb * 64 + (((hb + 1) ^ (rb & 7)) * 8);

    // compute: wave wv owns cols wv*16+[0,16), all 32 rows (2 A-frags)
    const int lane = tid & 63, wv = tid >> 6;
    const int fr = lane & 15, fs = lane >> 4;
    const int aB0 = fr * 64,        ax0 = fr & 7;
    const int aB1 = (16 + fr) * 64, ax1 = (16 + fr) & 7;
    const int bB  = (wv * 16 + fr) * 64, bx = (wv * 16 + fr) & 7;

    float a8[8], b16[16];
    f32x4 acc[2] = {(f32x4){0.f,0.f,0.f,0.f}, (f32x4){0.f,0.f,0.f,0.f}};

#define G3_LOAD(c)  do { \
        const int k0 = (c) * 64; \
        *(float4*)&a8[0]  = *(const float4*)(gA + k0); \
        *(float4*)&a8[4]  = *(const float4*)(gA + k0 + 4); \
        *(float4*)&b16[0] = *(const float4*)(gB + k0); \
        *(float4*)&b16[4] = *(const float4*)(gB + k0 + 4); \
        *(float4*)&b16[8] = *(const float4*)(gB + k0 + 8); \
        *(float4*)&b16[12]= *(const float4*)(gB + k0 + 12); \
    } while (0)

#define G3_WRITE(b) do { \
        s16x8 h_, l_; \
        split8(a8, h_, l_); \
        *(s16x8*)&sA[b][0][wA] = h_;  *(s16x8*)&sA[b][1][wA] = l_; \
        split8(&b16[0], h_, l_); \
        *(s16x8*)&sB[b][0][wB0] = h_; *(s16x8*)&sB[b][1][wB0] = l_; \
        split8(&b16[8], h_, l_); \
        *(s16x8*)&sB[b][0][wB1] = h_; *(s16x8*)&sB[b][1][wB1] = l_; \
    } while (0)

    G3_LOAD(0);
    G3_WRITE(0);

    for (int c = 0; c < 8; ++c) {
        const int p = c & 1;
        __syncthreads();                     // buf p written & prior reads done
        if (c < 7) G3_LOAD(c + 1);           // issued after barrier: latency
                                             // covered by compute below
        #pragma unroll
        for (int h = 0; h < 2; ++h) {
            const int sl = h * 4 + fs;
            s16x8 ah0 = *(const s16x8*)&sA[p][0][aB0 + ((sl ^ ax0) * 8)];
            s16x8 al0 = *(const s16x8*)&sA[p][1][aB0 + ((sl ^ ax0) * 8)];
            s16x8 ah1 = *(const s16x8*)&sA[p][0][aB1 + ((sl ^ ax1) * 8)];
            s16x8 al1 = *(const s16x8*)&sA[p][1][aB1 + ((sl ^ ax1) * 8)];
            s16x8 bh  = *(const s16x8*)&sB[p][0][bB  + ((sl ^ bx)  * 8)];
            s16x8 bl  = *(const s16x8*)&sB[p][1][bB  + ((sl ^ bx)  * 8)];
            acc[0] = __builtin_amdgcn_mfma_f32_16x16x32_bf16(ah0, bh, acc[0], 0, 0, 0);
            acc[0] = __builtin_amdgcn_mfma_f32_16x16x32_bf16(ah0, bl, acc[0], 0, 0, 0);
            acc[0] = __builtin_amdgcn_mfma_f32_16x16x32_bf16(al0, bh, acc[0], 0, 0, 0);
            acc[1] = __builtin_amdgcn_mfma_f32_16x16x32_bf16(ah1, bh, acc[1], 0, 0, 0);
            acc[1] = __builtin_amdgcn_mfma_f32_16x16x32_bf16(ah1, bl, acc[1], 0, 0, 0);
            acc[1] = __builtin_amdgcn_mfma_f32_16x16x32_bf16(al1, bh, acc[1], 0, 0, 0);
        }
        if (c < 7) G3_WRITE((c + 1) & 1);    // other buffer: no WAR with current
                                             // readers; visible after next barrier
    }
#undef G3_LOAD
#undef G3_WRITE

    // epilogue: C/D col=fr, row=fs*4+q within each 16x16 frag
    #pragma unroll
    for (int i = 0; i < 2; ++i)
        #pragma unroll
        for (int q = 0; q < 4; ++q)
            ws_mx[(size_t)(rt * 32 + i * 16 + fs * 4 + q) * HID_ + ct * 64 + wv * 16 + fr]
                = acc[i][q];
}

// ---------------------------------------------------------------------------
// Stage 1b: per-row mobius epilogue, ONE WAVE PER ROW (no barriers).
// ---------------------------------------------------------------------------
__global__ __launch_bounds__(256) void mobius_rows_kernel(
    const float* __restrict__ query,
    const float* __restrict__ bq, const float* __restrict__ bk,
    const float* __restrict__ bv,
    float* __restrict__ ws_qkv, float* __restrict__ ws_gamma)
{
    const int lane = threadIdx.x & 63;
    const int wv   = threadIdx.x >> 6;
    const int row  = blockIdx.x * 4 + wv;     // 0..1535
    const int which = row >> 9;
    const int rr    = row & 511;              // b*S + s
    const float* __restrict__ bias = (which == 0) ? bq : (which == 1) ? bk : bv;
    float* mrow = ws_qkv + (size_t)row * HID_;
    const float* xrow = query + (size_t)((rr & 255) * 2 + (rr >> 8)) * HID_;

    float m[8], x[8], bb[8];
    *(float4*)&m[0]  = ((const float4*)mrow)[lane * 2];
    *(float4*)&m[4]  = ((const float4*)mrow)[lane * 2 + 1];
    *(float4*)&x[0]  = ((const float4*)xrow)[lane * 2];
    *(float4*)&x[4]  = ((const float4*)xrow)[lane * 2 + 1];
    *(float4*)&bb[0] = ((const float4*)bias)[lane * 2];
    *(float4*)&bb[4] = ((const float4*)bias)[lane * 2 + 1];

    float x2p = 0.f, m2p = 0.f, b2p = 0.f;
    #pragma unroll
    for (int j = 0; j < 8; ++j) {
        x2p = fmaf(x[j], x[j], x2p);
        m2p = fmaf(m[j], m[j], m2p);
        b2p = fmaf(bb[j], bb[j], b2p);
    }
    const float x2s = wsum64(x2p);
    const float mn2 = wsum64(m2p);
    const float b2s = wsum64(b2p);
    const float xn = fmaxf(sqrtf(x2s), 1e-15f);
    const float mn = fmaxf(sqrtf(mn2), 1e-15f);
    // mobius_matvec: res = tanh(mn/xn * artanh(xn)) * mx/mn
    const float fac = tanhf(mn / xn * artanh_c(xn)) / mn;
    float r[8];
    float r2p = 0.f, ryp = 0.f;
    #pragma unroll
    for (int j = 0; j < 8; ++j) {
        r[j] = fac * m[j];
        r2p = fmaf(r[j], r[j], r2p);
        ryp = fmaf(r[j], bb[j], ryp);
    }
    const float r2s = wsum64(r2p);
    const float ry  = wsum64(ryp);
    // mobius_add(r, bias)
    const float a_c = 1.f + 2.f * ry + b2s;
    const float b_c = 1.f - r2s;
    const float den = 1.f + 2.f * ry + r2s * b2s;
    const float inv_den = 1.f / fmaxf(den, 1e-15f);
    float h[8];
    float h2p = 0.f;
    #pragma unroll
    for (int j = 0; j < 8; ++j) {
        h[j] = (a_c * r[j] + b_c * bb[j]) * inv_den;
        h2p = fmaf(h[j], h[j], h2p);
    }
    const float h2s = wsum64(h2p);
    float hn = fmaxf(sqrtf(h2s), 1e-15f);
    float pf = 1.f;
    if (hn > 0.996f) { pf = 0.996f / hn; hn = 0.996f; }   // projx
    const float lf = artanh_c(hn) / hn * pf;               // logmap0 (512-dim)
    float l[8];
    float l2p = 0.f;
    #pragma unroll
    for (int j = 0; j < 8; ++j) {
        l[j] = lf * h[j];
        l2p = fmaf(l[j], l[j], l2p);
    }
    // expmap0 over flat 64-chunks: chunk j = lanes j*8 .. j*8+7
    float cs = l2p;
    cs += __shfl_xor(cs, 1, 64);
    cs += __shfl_xor(cs, 2, 64);
    cs += __shfl_xor(cs, 4, 64);
    const float cn = fmaxf(sqrtf(cs), 1e-15f);
    const float th = tanhf(cn);
    const float sc = th / cn;
    float o[8];
    #pragma unroll
    for (int j = 0; j < 8; ++j) o[j] = sc * l[j];
    ((float4*)mrow)[lane * 2]     = *(float4*)&o[0];
    ((float4*)mrow)[lane * 2 + 1] = *(float4*)&o[4];
    if (which == 2 && (lane & 7) == 0) {
        const int j = lane >> 3;
        // gamma = 2 / max(1 - ||vl_chunk||^2, eps); ||vl_chunk|| = tanh(cn)
        ws_gamma[(size_t)rr * NH_ + j] = 2.f / fmaxf(1.f - th * th, 1e-15f);
    }
}

// ---------------------------------------------------------------------------
// Stage 2+3 FUSED, v3. Post-mortem of v1(39us)==v2(37us): per-n kv LDS
// re-reads (8x redundant across q-waves), mid-chain shfl merges, and v2's
// 128-VGPR cap (spill risk) were the suspects. v3 removes ALL LDS/shfl from
// the hot loop:
//   * thread = one K-row n (256 threads = 256 n). kv[64] in REGISTERS, read
//     once per thread from global (L2-hot, 64KB per bh); k2 in-reg.
//   * q-vector via wave-uniform pointer -> scalar(SMEM) loads, zero VGPR;
//     v_fma with SGPR operand. q-tile = 4 (block covers 4 q x 256 n).
//   * phase A per (q,n): dot 64 fma -> tail -> w-loop 64 fma + 64 rcp + adds,
//     4 independent accum chains, no cross-lane ops at all.
//   * grid 1024 (16 bh x 64 q-tiles) = exactly 4 blocks/CU, LDS 9KB,
//     est ~100 VGPR (no launch-bounds cap) -> 16 waves/CU without spills.
// Phase B: wave w owns n in [64w,64w+64), 4 q; p*g formed on the fly from
// pP/gS. denom folded into phase B prologue. Math identical to v1/v2.
// ---------------------------------------------------------------------------
__global__ __launch_bounds__(256) void attn_kernel(
    const float* __restrict__ ws_qkv, const float* __restrict__ gamma,
    float* __restrict__ probs, float* __restrict__ lc)
{
    const int tid = threadIdx.x;
    const int bh  = blockIdx.x & 15;
    const int q0  = (blockIdx.x >> 4) * 4;        // 0..252
    const float* __restrict__ ql = ws_qkv + (size_t)bh * (S_ * HD_);
    const float* __restrict__ kl = ws_qkv + (size_t)BSH + (size_t)bh * (S_ * HD_);
    const float* __restrict__ vl = ws_qkv + (size_t)2 * BSH + (size_t)bh * (S_ * HD_);

    __shared__ float pP[4][256];       // raw p, [q_local][n]     4 KB
    __shared__ float gS[S_];           //                         1 KB
    __shared__ float nomP[4][4][64];   // phase-B partials        4 KB
    __shared__ float q2S[4];
    __shared__ float dnS[4];

    gS[tid] = gamma[(size_t)bh * S_ + tid];

    // kv: this thread's K-row, registers. L2-hot (64KB/bh shared by 64 blocks).
    const int n = tid;
    float kv[64];
    #pragma unroll
    for (int c = 0; c < 16; ++c)
        *(float4*)&kv[c * 4] = *(const float4*)(kl + (size_t)n * 64 + c * 4);
    float k2a = 0.f, k2b = 0.f;
    #pragma unroll
    for (int d = 0; d < 64; d += 2) {
        k2a = fmaf(kv[d],     kv[d],     k2a);
        k2b = fmaf(kv[d + 1], kv[d + 1], k2b);
    }
    const float k2 = k2a + k2b;

    // |q|^2 for the 4 q of this tile: threads 0..3 each compute one (others idle
    // ~128 cycles; negligible), then broadcast via LDS.
    if (tid < 4) {
        const float* qr = ql + (size_t)(q0 + tid) * 64;
        float s = 0.f;
        #pragma unroll
        for (int d = 0; d < 64; ++d) s = fmaf(qr[d], qr[d], s);
        q2S[tid] = s;
    }
    __syncthreads();

    #pragma unroll
    for (int q = 0; q < 4; ++q) {
        const float* __restrict__ qrow = ql + (size_t)(q0 + q) * 64;  // uniform -> s_load
        const float q2  = q2S[q];
        const float b_c = 1.f - q2;
        // dot(q, k): 4 chains
        float s0 = 0.f, s1 = 0.f, s2 = 0.f, s3 = 0.f;
        #pragma unroll
        for (int d = 0; d < 64; d += 4) {
            s0 = fmaf(kv[d],     qrow[d],     s0);
            s1 = fmaf(kv[d + 1], qrow[d + 1], s1);
            s2 = fmaf(kv[d + 2], qrow[d + 2], s2);
            s3 = fmaf(kv[d + 3], qrow[d + 3], s3);
        }
        const float s = (s0 + s1) + (s2 + s3);
        const float a_c = 1.f - 2.f * s + k2;
        const float den = fmaxf(fmaf(q2, k2, 1.f - 2.f * s), 1e-15f);
        const float ra  = __builtin_amdgcn_rcpf(a_c);
        const float r_c = b_c * ra;
        const float scale = den * den * ra * ra;   // den^2 / a_c^2
        const float c2  = 1e-30f * scale;
        float i0 = 0.f, i1 = 0.f, i2 = 0.f, i3 = 0.f;
        #pragma unroll
        for (int d = 0; d < 64; d += 4) {
            const float w0 = fmaf(r_c, kv[d],     -qrow[d]);
            const float w1 = fmaf(r_c, kv[d + 1], -qrow[d + 1]);
            const float w2 = fmaf(r_c, kv[d + 2], -qrow[d + 2]);
            const float w3 = fmaf(r_c, kv[d + 3], -qrow[d + 3]);
            i0 += __builtin_amdgcn_rcpf(fmaf(w0, w0, c2));
            i1 += __builtin_amdgcn_rcpf(fmaf(w1, w1, c2));
            i2 += __builtin_amdgcn_rcpf(fmaf(w2, w2, c2));
            i3 += __builtin_amdgcn_rcpf(fmaf(w3, w3, c2));
        }
        const float invsum = (i0 + i1) + (i2 + i3);
        const float t1 = __builtin_amdgcn_rsqf(scale * invsum);
        const float p = 0.5f - 0.5f * fminf(t1, 0.9999999f);
        probs[((size_t)(bh * S_ + q0 + q)) * S_ + n] = p;   // coalesced over n
        pP[q][n] = p;
    }
    __syncthreads();

    // denom (phase-B prologue): wave w handles q=w
    const int w = tid >> 6, d = tid & 63;
    {
        float sp = 0.f, spg = 0.f;
        #pragma unroll
        for (int m = 0; m < 4; ++m) {
            const float p = pP[w][d + 64 * m];
            const float g = gS[d + 64 * m];
            sp += p; spg = fmaf(p, g, spg);
        }
        sp = wsum64(sp);
        spg = wsum64(spg);
        if (d == 0) dnS[w] = spg - sp;   // denom = sum p*(g-1)
    }

    // Phase B: wave w owns n in [64w, 64w+64), all 4 q; lane = d
    float acc[4] = {};
    const float* __restrict__ vbase = vl + (size_t)(w * 64) * 64;
    #pragma unroll 4
    for (int i4 = 0; i4 < 16; ++i4) {
        float gv[4];
        const float4 g4 = *(const float4*)&gS[w * 64 + i4 * 4];     // uniform
        #pragma unroll
        for (int j2 = 0; j2 < 4; ++j2)
            gv[j2] = ((const float*)&g4)[j2] * vbase[(size_t)(i4 * 4 + j2) * 64 + d];
        #pragma unroll
        for (int qq = 0; qq < 4; ++qq) {
            const float4 pq = *(const float4*)&pP[qq][w * 64 + i4 * 4];   // uniform
            acc[qq] = fmaf(pq.x, gv[0], acc[qq]);
            acc[qq] = fmaf(pq.y, gv[1], acc[qq]);
            acc[qq] = fmaf(pq.z, gv[2], acc[qq]);
            acc[qq] = fmaf(pq.w, gv[3], acc[qq]);
        }
    }
    #pragma unroll
    for (int qq = 0; qq < 4; ++qq) nomP[w][qq][d] = acc[qq];
    __syncthreads();

    // final: thread owns (q = w, d); whole wave shares one q
    {
        const int qq = w;
        float nom = 0.f;
        #pragma unroll
        for (int w2 = 0; w2 < 4; ++w2) nom += nomP[w2][qq][d];
        const float dd = dnS[qq];
        const float adn = fmaxf(fabsf(dd), 1e-10f);
        const float sden = (dd >= 0.f) ? adn : -adn;
        const float m = nom / sden;
        const float ss = wsum64(m * m);
        const float nn = fmaxf(sqrtf(ss), 1e-15f);
        const float s1 = tanhf(0.5f * artanh_c(nn));     // mobius_scalar_mul(0.5)
        const float res = s1 * m / nn;
        const float nres = fmaxf(s1, 1e-15f);            // ||res|| = s1 >= 0
        lc[((size_t)(bh * S_ + q0 + qq)) * HD_ + d] = (artanh_c(nres) / nres) * res;
    }
}

// ---------------------------------------------------------------------------
// Stage 4: gather heads -> [B,Q,512] row, expmap0 over 512, store [S,B,HID].
// ---------------------------------------------------------------------------
__global__ __launch_bounds__(256) void outproj_kernel(
    const float* __restrict__ lc, float* __restrict__ out0)
{
    const int t = threadIdx.x;
    const int s = blockIdx.x & (S_ - 1);
    const int b = blockIdx.x >> 8;
    __shared__ float red[256];
    const int h0 = t >> 6, d0 = t & 63;
    const int e1 = t + 256;
    const int h1 = e1 >> 6, d1 = e1 & 63;
    const float v0 = lc[(((size_t)(b * NH_ + h0)) * S_ + s) * HD_ + d0];
    const float v1 = lc[(((size_t)(b * NH_ + h1)) * S_ + s) * HD_ + d1];
    const float ss = block_sum_256(v0 * v0 + v1 * v1, red);
    const float nn = fmaxf(sqrtf(ss), 1e-15f);
    const float f = tanhf(nn) / nn;
    float* orow = out0 + ((size_t)(s * B_ + b)) * HID_;
    orow[t] = f * v0;
    orow[t + 256] = f * v1;
}

extern "C" void kernel_launch(void* const* d_in, const int* in_sizes, int n_in,
                              void* d_out, int out_size, void* d_ws, size_t ws_size,
                              hipStream_t stream) {
    (void)in_sizes; (void)n_in; (void)out_size; (void)ws_size;
    const float* query = (const float*)d_in[0];
    const float* Wq = (const float*)d_in[1];
    const float* bq = (const float*)d_in[2];
    const float* Wk = (const float*)d_in[3];
    const float* bk = (const float*)d_in[4];
    const float* Wv = (const float*)d_in[5];
    const float* bv = (const float*)d_in[6];

    float* out0  = (float*)d_out;                          // [S,B,HID] = 262144
    float* probs = out0 + (size_t)S_ * B_ * HID_;          // [B,NH,S,S] = 1048576

    float* ws       = (float*)d_ws;
    float* ws_qkv   = ws;                                  // mx -> ql|kl|vl : 3*262144 floats
    float* ws_gamma = ws + (size_t)3 * BSH;                // 4096 floats, flat chunk order
    float* ws_lc    = ws + (size_t)3 * BSH + 4096;         // 131072 floats (NO alias: attn
                                                           // writes lc while other blocks read ql)

    gemm3_fused_kernel<<<dim3(384), dim3(256), 0, stream>>>(query, Wq, Wk, Wv, ws_qkv);
    mobius_rows_kernel<<<dim3(384), dim3(256), 0, stream>>>(query, bq, bk, bv, ws_qkv, ws_gamma);
    attn_kernel<<<dim3(1024), dim3(256), 0, stream>>>(ws_qkv, ws_gamma, probs, ws_lc);
    outproj_kernel<<<dim3(B_ * S_), dim3(256), 0, stream>>>(ws_lc, out0);
}